// Round 3
// baseline (390.541 us; speedup 1.0000x reference)
//
#include <hip/hip_runtime.h>
#include <hip/hip_bf16.h>

#define NB 32
#define NN 128
#define NE 16256
#define ND 64
#define NHID 128
#define NM 128
#define NOH 256
#define NT 2
#define EHALF 8128
#define NTILE 127        // 64-edge tiles per half (127*64 == 8128 exactly)
#define TILE_E 64

typedef short s16x8 __attribute__((ext_vector_type(8)));
typedef short s16x4 __attribute__((ext_vector_type(4)));
typedef float f32x4 __attribute__((ext_vector_type(4)));

#define MFMA16(a, b, c) __builtin_amdgcn_mfma_f32_16x16x32_bf16((a), (b), (c), 0, 0, 0)

// ---- ws layout (bytes) ----
// partial: bf16 [512][m=128][n=128]
#define PARTIAL_SZ ((size_t)512 * 128 * 128 * 2)          // 16,777,216
#define WS_RS      (PARTIAL_SZ)                           // ushort[NE][128]
#define RS_SZ      ((size_t)NE * 128 * 2)                 //  4,161,536
#define WS_RRT     (WS_RS + RS_SZ)                        // ushort[128][NE]
#define RRT_SZ     ((size_t)128 * NE * 2)                 //  4,161,536
#define WS_IWA     (WS_RRT + RRT_SZ)                      // ushort[b][half][it][h=128][n=128]
#define IWA_SZ     ((size_t)NB * 2 * 2 * 128 * 128 * 2)   //  8,388,608
// total = 33,488,896 B = 31.94 MB  (<= proven 32 MB)

__device__ __forceinline__ ushort f2bf(float x) {
    uint u = __float_as_uint(x);
    return (ushort)((u + 0x7fffu + ((u >> 16) & 1u)) >> 16);
}
__device__ __forceinline__ float bf2f(ushort h) {
    return __uint_as_float(((uint)h) << 16);
}
__device__ __forceinline__ float4 ldg4(const float* p) {
    return *reinterpret_cast<const float4*>(p);
}
// XOR-swizzle within a row (G4): byte ^= (row&7)<<4
__device__ __forceinline__ char* swz(void* base, int row, int rowBytes, int bir) {
    return (char*)base + row * rowBytes + (bir ^ ((row & 7) << 4));
}
__device__ __forceinline__ const char* swzc(const void* base, int row, int rowBytes, int bir) {
    return (const char*)base + row * rowBytes + (bir ^ ((row & 7) << 4));
}

// ---------------------------------------------------------------------------
// k_cvt: blocks 0..126: rrT transpose+convert; 127..253: rs convert
// ---------------------------------------------------------------------------
__global__ __launch_bounds__(256)
void k_cvt(const float* __restrict__ rel_rec, const float* __restrict__ rel_send,
           char* __restrict__ ws)
{
    ushort* rs  = (ushort*)(ws + WS_RS);
    ushort* rrT = (ushort*)(ws + WS_RRT);
    const int t = threadIdx.x;
    const int blk = blockIdx.x;
    __shared__ float lds[128][65];

    if (blk < 127) {                       // rrT: transpose rel_rec -> [n][e] bf16
        const int eb = blk;
        for (int nh = 0; nh < 2; ++nh) {
            __syncthreads();
            for (int i = t; i < 128 * 64; i += 256) {
                int e = i >> 6, n = i & 63;
                lds[e][n] = rel_rec[(size_t)(eb * 128 + e) * 128 + nh * 64 + n];
            }
            __syncthreads();
            for (int i = t; i < 64 * 128; i += 256) {
                int n = i >> 7, e = i & 127;
                rrT[(size_t)(nh * 64 + n) * NE + eb * 128 + e] = f2bf(lds[e][n]);
            }
        }
    } else {                               // rs: straight convert
        const int eb = blk - 127;
        const float4* src = (const float4*)(rel_send + (size_t)eb * 16384);
        for (int i = t; i < 4096; i += 256) {
            float4 v = src[i];
            ushort4 o;
            o.x = f2bf(v.x); o.y = f2bf(v.y); o.z = f2bf(v.z); o.w = f2bf(v.w);
            *(ushort4*)(rs + (size_t)eb * 16384 + (size_t)i * 4) = o;
        }
    }
}

// ---------------------------------------------------------------------------
// k_prep: inpWA[b][half][it][h][n] = sum_d WA[half,it][h][d] * inp[b][n][d]
// grid 128 = b*4 + half*2 + it, block 256 (4 waves).
// ---------------------------------------------------------------------------
__global__ __launch_bounds__(256)
void k_prep(const float* __restrict__ inputs,
            const float* __restrict__ w1, const float* __restrict__ w3,
            char* __restrict__ ws)
{
    ushort* iwa = (ushort*)(ws + WS_IWA);
    const int wg = blockIdx.x;
    const int b = wg >> 2, half = (wg >> 1) & 1, it = wg & 1;
    const float* WA  = (half ? w3 : w1) + (size_t)it * NHID * ND;
    const float* inp = inputs + (size_t)b * NN * ND;
    ushort* dst = iwa + (size_t)wg * NHID * NN;    // [h][n]

    const int lane = threadIdx.x & 63, wave = threadIdx.x >> 6;
    const int l16 = lane & 15, l4 = lane >> 4;

    for (int hh = 0; hh < 2; ++hh) {
        const int ht = wave * 2 + hh;
        s16x8 bf[2];
#pragma unroll
        for (int ks = 0; ks < 2; ++ks) {
            const float* p = WA + (size_t)(ht * 16 + l16) * ND + ks * 32 + l4 * 8;
            float4 u = ldg4(p), v = ldg4(p + 4);
            s16x8 f;
            f[0] = (short)f2bf(u.x); f[1] = (short)f2bf(u.y);
            f[2] = (short)f2bf(u.z); f[3] = (short)f2bf(u.w);
            f[4] = (short)f2bf(v.x); f[5] = (short)f2bf(v.y);
            f[6] = (short)f2bf(v.z); f[7] = (short)f2bf(v.w);
            bf[ks] = f;
        }
        for (int nt = 0; nt < 8; ++nt) {
            s16x8 af[2];
#pragma unroll
            for (int ks = 0; ks < 2; ++ks) {
                const float* p = inp + (size_t)(nt * 16 + l16) * ND + ks * 32 + l4 * 8;
                float4 u = ldg4(p), v = ldg4(p + 4);
                s16x8 f;
                f[0] = (short)f2bf(u.x); f[1] = (short)f2bf(u.y);
                f[2] = (short)f2bf(u.z); f[3] = (short)f2bf(u.w);
                f[4] = (short)f2bf(v.x); f[5] = (short)f2bf(v.y);
                f[6] = (short)f2bf(v.z); f[7] = (short)f2bf(v.w);
                af[ks] = f;
            }
            f32x4 c = (f32x4){0.f, 0.f, 0.f, 0.f};
            c = MFMA16(af[0], bf[0], c);
            c = MFMA16(af[1], bf[1], c);
            s16x4 o;
            o[0] = (short)f2bf(c[0]); o[1] = (short)f2bf(c[1]);
            o[2] = (short)f2bf(c[2]); o[3] = (short)f2bf(c[3]);
            *(s16x4*)&dst[(size_t)(ht * 16 + l16) * NN + nt * 16 + l4 * 4] = o;
        }
    }
}

// ---------------------------------------------------------------------------
// k_edge: H = relu(RS@inpWA + bA); M = sum_it relu(H@WB^T + bB)*rt;
//         agg += rrT@M.  grid 512 = b*16 + half*8 + chunk, block 512 (8 waves).
// 4 barriers per 64-edge tile; 2 blocks/CU.
// ---------------------------------------------------------------------------
__global__ __launch_bounds__(512, 4)
void k_edge(const float* __restrict__ rel_type, const int* __restrict__ indices,
            const float* __restrict__ b1, const float* __restrict__ b2,
            const float* __restrict__ b3, const float* __restrict__ b4,
            const float* __restrict__ w2, const float* __restrict__ w4,
            char* __restrict__ ws)
{
    const ushort* rs  = (const ushort*)(ws + WS_RS);
    const ushort* rrT = (const ushort*)(ws + WS_RRT);
    const ushort* iwa = (const ushort*)(ws + WS_IWA);
    ushort* partial   = (ushort*)ws;

    const int tid  = threadIdx.x;
    const int wave = tid >> 6;
    const int lane = tid & 63;
    const int l16  = lane & 15;
    const int l4   = lane >> 4;

    const int wg    = blockIdx.x;
    const int b     = wg >> 4;
    const int half  = (wg >> 3) & 1;
    const int chunk = wg & 7;

    const float* BA    = half ? b3 : b1;
    const float* BB    = half ? b4 : b2;
    const float* WBsrc = half ? w4 : w2;

    __shared__ ushort H_s[2][64 * 128];   // 32 KB, rows 256B (e-major, per it)
    __shared__ ushort Mt_s[128 * 64];     // 16 KB, rows 128B (m-major)
    __shared__ ushort rr_s[128 * 64];     // 16 KB, rows 128B (n-major)
    __shared__ int    idx_s[64];
    __shared__ float  rt_s[128];

    // persistent B-fragments
    s16x8 wIW[2][4];   // inpWA [it][ks]: lane col h = wave*16+l16, k = n
    const ushort* iwb = iwa + (size_t)((b * 2 + half) * 2) * NHID * NN;
#pragma unroll
    for (int it = 0; it < 2; ++it)
#pragma unroll
        for (int ks = 0; ks < 4; ++ks)
            wIW[it][ks] = *(const s16x8*)(iwb + (size_t)it * NHID * NN +
                                          (size_t)(wave * 16 + l16) * NN + ks * 32 + l4 * 8);
    s16x8 wB[2][4];    // WB [it][ks]: lane col m = wave*16+l16, k = h (cvt from f32)
#pragma unroll
    for (int it = 0; it < 2; ++it)
#pragma unroll
        for (int ks = 0; ks < 4; ++ks) {
            const float* p = WBsrc + (size_t)(it * NM + wave * 16 + l16) * NHID + ks * 32 + l4 * 8;
            float4 u = ldg4(p), v = ldg4(p + 4);
            s16x8 f;
            f[0] = (short)f2bf(u.x); f[1] = (short)f2bf(u.y);
            f[2] = (short)f2bf(u.z); f[3] = (short)f2bf(u.w);
            f[4] = (short)f2bf(v.x); f[5] = (short)f2bf(v.y);
            f[6] = (short)f2bf(v.z); f[7] = (short)f2bf(v.w);
            wB[it][ks] = f;
        }
    float biasA[2] = {BA[wave * 16 + l16], BA[NHID + wave * 16 + l16]};
    float biasB[2] = {BB[wave * 16 + l16], BB[NM + wave * 16 + l16]};

    f32x4 agg[8];
#pragma unroll
    for (int r = 0; r < 8; ++r) agg[r] = (f32x4){0.f, 0.f, 0.f, 0.f};

    const int t0 = chunk * 16;
    const int t1 = (t0 + 16 < NTILE) ? (t0 + 16) : NTILE;

    for (int tile = t0; tile < t1; ++tile) {
        const int e_base = tile * TILE_E;
        __syncthreads();                                   // (A)
        if (tid < 64) {
            idx_s[tid] = indices[half * EHALF + e_base + tid];
        } else if (tid < 192) {
            int q = tid - 64, e = q >> 1, it = q & 1;
            int eg = indices[half * EHALF + e_base + e];
            rt_s[q] = rel_type[((size_t)b * NE + eg) * NT + it];
        }
        __syncthreads();                                   // (B)

        // stage rr_s (consumed in agg, after (D))
        const int eg0 = idx_s[0];
        for (int i = tid; i < 1024; i += 512) {
            int n = i >> 3, c = i & 7;
            s16x8 v = *(const s16x8*)(rrT + (size_t)n * NE + eg0 + c * 8);
            *(s16x8*)swz(rr_s, n, 128, c * 16) = v;
        }

        // ---- H phase: H[it] = relu(RS @ inpWA[it] + bA[it]) ----
        for (int et = 0; et < 4; ++et) {
            const int erow = et * 16 + l16;
            const ushort* arow = rs + (size_t)idx_s[erow] * 128 + l4 * 8;
            s16x8 a0 = *(const s16x8*)(arow);
            s16x8 a1 = *(const s16x8*)(arow + 32);
            s16x8 a2 = *(const s16x8*)(arow + 64);
            s16x8 a3 = *(const s16x8*)(arow + 96);
#pragma unroll
            for (int it = 0; it < 2; ++it) {
                f32x4 c = (f32x4){0.f, 0.f, 0.f, 0.f};
                __builtin_amdgcn_s_setprio(1);
                c = MFMA16(a0, wIW[it][0], c);
                c = MFMA16(a1, wIW[it][1], c);
                c = MFMA16(a2, wIW[it][2], c);
                c = MFMA16(a3, wIW[it][3], c);
                __builtin_amdgcn_s_setprio(0);
#pragma unroll
                for (int r = 0; r < 4; ++r) {
                    int er = et * 16 + l4 * 4 + r;
                    *(ushort*)swz(&H_s[it][0], er, 256, (wave * 16 + l16) * 2) =
                        f2bf(fmaxf(c[r] + biasA[it], 0.f));
                }
            }
        }
        __syncthreads();                                   // (C)

        // ---- M phase: msg = sum_it relu(H[it] @ WB[it]^T + bB[it]) * rt ----
        float msg_acc[4][4];
#pragma unroll
        for (int et = 0; et < 4; ++et)
#pragma unroll
            for (int r = 0; r < 4; ++r) msg_acc[et][r] = 0.f;

        for (int et = 0; et < 4; ++et) {
            const int e = et * 16 + l16;
#pragma unroll
            for (int it = 0; it < 2; ++it) {
                f32x4 c = (f32x4){0.f, 0.f, 0.f, 0.f};
                __builtin_amdgcn_s_setprio(1);
#pragma unroll
                for (int ks = 0; ks < 4; ++ks) {
                    s16x8 a = *(const s16x8*)swzc(&H_s[it][0], e, 256, (ks * 32 + l4 * 8) * 2);
                    c = MFMA16(a, wB[it][ks], c);
                }
                __builtin_amdgcn_s_setprio(0);
#pragma unroll
                for (int r = 0; r < 4; ++r) {
                    int er = et * 16 + l4 * 4 + r;
                    msg_acc[et][r] += fmaxf(c[r] + biasB[it], 0.f) * rt_s[er * 2 + it];
                }
            }
        }
        // write Mt (m-major)
        {
            const int m = wave * 16 + l16;
#pragma unroll
            for (int et = 0; et < 4; ++et) {
                s16x4 v;
                v[0] = (short)f2bf(msg_acc[et][0]);
                v[1] = (short)f2bf(msg_acc[et][1]);
                v[2] = (short)f2bf(msg_acc[et][2]);
                v[3] = (short)f2bf(msg_acc[et][3]);
                *(s16x4*)swz(Mt_s, m, 128, (et * 16 + l4 * 4) * 2) = v;
            }
        }
        __syncthreads();                                   // (D)

        // ---- agg += rrT @ msg ----
        {
            const int m = wave * 16 + l16;
            s16x8 bb0 = *(const s16x8*)swzc(Mt_s, m, 128, (l4 * 8) * 2);
            s16x8 bb1 = *(const s16x8*)swzc(Mt_s, m, 128, (32 + l4 * 8) * 2);
            __builtin_amdgcn_s_setprio(1);
#pragma unroll
            for (int nt = 0; nt < 8; ++nt) {
                int n = nt * 16 + l16;
                s16x8 a0 = *(const s16x8*)swzc(rr_s, n, 128, (l4 * 8) * 2);
                s16x8 a1 = *(const s16x8*)swzc(rr_s, n, 128, (32 + l4 * 8) * 2);
                agg[nt] = MFMA16(a0, bb0, agg[nt]);
                agg[nt] = MFMA16(a1, bb1, agg[nt]);
            }
            __builtin_amdgcn_s_setprio(0);
        }
    }

    // store bf16 partialT [wg][m][n] (vector s16x4)
    {
        ushort* dst = partial + (size_t)wg * (NN * NM);
        const int m = wave * 16 + l16;
#pragma unroll
        for (int nt = 0; nt < 8; ++nt) {
            s16x4 v;
            v[0] = (short)f2bf(agg[nt][0]);
            v[1] = (short)f2bf(agg[nt][1]);
            v[2] = (short)f2bf(agg[nt][2]);
            v[3] = (short)f2bf(agg[nt][3]);
            *(s16x4*)&dst[(size_t)m * NN + nt * 16 + l4 * 4] = v;
        }
    }
}

// ---------------------------------------------------------------------------
// k_out: reduce 16 bf16 partials -> node MLP 128->256->256->64 + residual
// ---------------------------------------------------------------------------
__global__ __launch_bounds__(256)
void k_out(const ushort* __restrict__ partial,
           const float* __restrict__ inputs,
           const float* __restrict__ ow1, const float* __restrict__ ob1,
           const float* __restrict__ ow2, const float* __restrict__ ob2,
           const float* __restrict__ ow3, const float* __restrict__ ob3,
           float* __restrict__ out)
{
    const int t  = threadIdx.x;
    const int wg = blockIdx.x;      // 0..255
    const int b  = wg >> 3;
    const int n0 = (wg & 7) * 16;

    __shared__ float xr[16 * NM];
    __shared__ float h1[16 * NOH];
    __shared__ float h2[16 * NOH];

    // reduce 16 partials (transposed layout [m][n])
    for (int u = t; u < 512; u += 256) {
        const int m = u >> 2, g = u & 3;
        float s0 = 0.f, s1 = 0.f, s2 = 0.f, s3 = 0.f;
#pragma unroll
        for (int c = 0; c < 16; ++c) {
            const ushort* p = partial + ((size_t)(b * 16 + c)) * (NN * NM) +
                              (size_t)m * NN + n0 + g * 4;
            s16x4 v = *(const s16x4*)p;
            s0 += bf2f((ushort)v[0]); s1 += bf2f((ushort)v[1]);
            s2 += bf2f((ushort)v[2]); s3 += bf2f((ushort)v[3]);
        }
        xr[(g * 4 + 0) * NM + m] = s0;
        xr[(g * 4 + 1) * NM + m] = s1;
        xr[(g * 4 + 2) * NM + m] = s2;
        xr[(g * 4 + 3) * NM + m] = s3;
    }
    __syncthreads();

    {
        float acc[16];
        const float bias = ob1[t];
#pragma unroll
        for (int r = 0; r < 16; ++r) acc[r] = bias;
        const float* wrow = ow1 + (size_t)t * NM;
#pragma unroll 2
        for (int mq = 0; mq < NM / 4; ++mq) {
            const float4 w = ldg4(wrow + mq * 4);
#pragma unroll
            for (int r = 0; r < 16; ++r) {
                const float4 xv = *reinterpret_cast<const float4*>(&xr[r * NM + mq * 4]);
                acc[r] += xv.x * w.x + xv.y * w.y + xv.z * w.z + xv.w * w.w;
            }
        }
#pragma unroll
        for (int r = 0; r < 16; ++r) h1[r * NOH + t] = fmaxf(acc[r], 0.f);
    }
    __syncthreads();

    {
        float acc[16];
        const float bias = ob2[t];
#pragma unroll
        for (int r = 0; r < 16; ++r) acc[r] = bias;
        const float* wrow = ow2 + (size_t)t * NOH;
#pragma unroll 2
        for (int hq = 0; hq < NOH / 4; ++hq) {
            const float4 w = ldg4(wrow + hq * 4);
#pragma unroll
            for (int r = 0; r < 16; ++r) {
                const float4 hv = *reinterpret_cast<const float4*>(&h1[r * NOH + hq * 4]);
                acc[r] += hv.x * w.x + hv.y * w.y + hv.z * w.z + hv.w * w.w;
            }
        }
#pragma unroll
        for (int r = 0; r < 16; ++r) h2[r * NOH + t] = fmaxf(acc[r], 0.f);
    }
    __syncthreads();

    {
        const int d  = t & 63;
        const int rg = t >> 6;
        float acc[4] = {0.f, 0.f, 0.f, 0.f};
        const float* wrow = ow3 + (size_t)d * NOH;
#pragma unroll 2
        for (int hq = 0; hq < NOH / 4; ++hq) {
            const float4 w = ldg4(wrow + hq * 4);
#pragma unroll
            for (int r = 0; r < 4; ++r) {
                const float4 hv = *reinterpret_cast<const float4*>(&h2[(rg * 4 + r) * NOH + hq * 4]);
                acc[r] += hv.x * w.x + hv.y * w.y + hv.z * w.z + hv.w * w.w;
            }
        }
        const float bias = ob3[d];
#pragma unroll
        for (int r = 0; r < 4; ++r) {
            const int n = n0 + rg * 4 + r;
            const size_t idx = ((size_t)b * NN + n) * ND + d;
            out[idx] = inputs[idx] + acc[r] + bias;
        }
    }
}

extern "C" void kernel_launch(void* const* d_in, const int* in_sizes, int n_in,
                              void* d_out, int out_size, void* d_ws, size_t ws_size,
                              hipStream_t stream)
{
    const float* inputs   = (const float*)d_in[0];
    const float* rel_rec  = (const float*)d_in[1];
    const float* rel_send = (const float*)d_in[2];
    const float* rel_type = (const float*)d_in[3];
    const int*   indices  = (const int*)  d_in[4];
    const float* w1  = (const float*)d_in[5];
    const float* b1  = (const float*)d_in[6];
    const float* w2  = (const float*)d_in[7];
    const float* b2  = (const float*)d_in[8];
    const float* w3  = (const float*)d_in[9];
    const float* b3  = (const float*)d_in[10];
    const float* w4  = (const float*)d_in[11];
    const float* b4  = (const float*)d_in[12];
    const float* ow1 = (const float*)d_in[13];
    const float* ob1 = (const float*)d_in[14];
    const float* ow2 = (const float*)d_in[15];
    const float* ob2 = (const float*)d_in[16];
    const float* ow3 = (const float*)d_in[17];
    const float* ob3 = (const float*)d_in[18];

    char* ws = (char*)d_ws;

    k_cvt <<<dim3(254), dim3(256), 0, stream>>>(rel_rec, rel_send, ws);
    k_prep<<<dim3(128), dim3(256), 0, stream>>>(inputs, w1, w3, ws);
    k_edge<<<dim3(512), dim3(512), 0, stream>>>(rel_type, indices,
                                                b1, b2, b3, b4, w2, w4, ws);
    k_out <<<dim3(256), dim3(256), 0, stream>>>((const ushort*)ws, inputs,
                                                ow1, ob1, ow2, ob2, ow3, ob3,
                                                (float*)d_out);
}

// Round 4
// 307.157 us; speedup vs baseline: 1.2715x; 1.2715x over previous
//
#include <hip/hip_runtime.h>
#include <hip/hip_bf16.h>

#define NB 32
#define NN 128
#define NE 16256
#define ND 64
#define NHID 128
#define NM 128
#define NOH 256
#define NT 2
#define EHALF 8128
#define NTILE 127        // 64-edge tiles per half (127*64 == 8128 exactly)
#define TILE_E 64

typedef short s16x8 __attribute__((ext_vector_type(8)));
typedef short s16x4 __attribute__((ext_vector_type(4)));
typedef float f32x4 __attribute__((ext_vector_type(4)));

#define MFMA16(a, b, c) __builtin_amdgcn_mfma_f32_16x16x32_bf16((a), (b), (c), 0, 0, 0)

// ---- ws layout (bytes) ----
// partial: bf16 [512][m=128][n=128]
#define PARTIAL_SZ ((size_t)512 * 128 * 128 * 2)          // 16,777,216
#define WS_RS      (PARTIAL_SZ)                           // ushort[NE][128]
#define RS_SZ      ((size_t)NE * 128 * 2)                 //  4,161,536
#define WS_RRT     (WS_RS + RS_SZ)                        // ushort[128][NE]
#define RRT_SZ     ((size_t)128 * NE * 2)                 //  4,161,536
#define WS_IWA     (WS_RRT + RRT_SZ)                      // ushort[b][half][it][h=128][n=128]
#define IWA_SZ     ((size_t)NB * 2 * 2 * 128 * 128 * 2)   //  8,388,608
// total = 33,488,896 B = 31.94 MB  (<= proven 32 MB)

__device__ __forceinline__ ushort f2bf(float x) {
    uint u = __float_as_uint(x);
    return (ushort)((u + 0x7fffu + ((u >> 16) & 1u)) >> 16);
}
__device__ __forceinline__ float bf2f(ushort h) {
    return __uint_as_float(((uint)h) << 16);
}
__device__ __forceinline__ float4 ldg4(const float* p) {
    return *reinterpret_cast<const float4*>(p);
}
// XOR-swizzle within a row (G4): byte ^= (row&7)<<4
__device__ __forceinline__ char* swz(void* base, int row, int rowBytes, int bir) {
    return (char*)base + row * rowBytes + (bir ^ ((row & 7) << 4));
}
__device__ __forceinline__ const char* swzc(const void* base, int row, int rowBytes, int bir) {
    return (const char*)base + row * rowBytes + (bir ^ ((row & 7) << 4));
}

// ---------------------------------------------------------------------------
// k_pre: fused conversions + inpWA precompute.
// blocks 0..126: rrT transpose+convert; 127..253: rs convert;
// blocks 254..381: inpWA[b][half][it] = (inp[b] @ WA^T) in bf16 [h][n]
// ---------------------------------------------------------------------------
__global__ __launch_bounds__(256)
void k_pre(const float* __restrict__ inputs,
           const float* __restrict__ rel_rec, const float* __restrict__ rel_send,
           const float* __restrict__ w1, const float* __restrict__ w3,
           char* __restrict__ ws)
{
    ushort* rs  = (ushort*)(ws + WS_RS);
    ushort* rrT = (ushort*)(ws + WS_RRT);
    const int t = threadIdx.x;
    const int blk = blockIdx.x;
    __shared__ float lds[128][65];

    if (blk < 127) {                       // rrT: transpose rel_rec -> [n][e] bf16
        const int eb = blk;
        for (int nh = 0; nh < 2; ++nh) {
            __syncthreads();
            for (int i = t; i < 128 * 64; i += 256) {
                int e = i >> 6, n = i & 63;
                lds[e][n] = rel_rec[(size_t)(eb * 128 + e) * 128 + nh * 64 + n];
            }
            __syncthreads();
            for (int i = t; i < 64 * 128; i += 256) {
                int n = i >> 7, e = i & 127;
                rrT[(size_t)(nh * 64 + n) * NE + eb * 128 + e] = f2bf(lds[e][n]);
            }
        }
    } else if (blk < 254) {                // rs: straight convert
        const int eb = blk - 127;
        const float4* src = (const float4*)(rel_send + (size_t)eb * 16384);
        for (int i = t; i < 4096; i += 256) {
            float4 v = src[i];
            ushort4 o;
            o.x = f2bf(v.x); o.y = f2bf(v.y); o.z = f2bf(v.z); o.w = f2bf(v.w);
            *(ushort4*)(rs + (size_t)eb * 16384 + (size_t)i * 4) = o;
        }
    } else {                               // inpWA precompute (MFMA)
        ushort* iwa = (ushort*)(ws + WS_IWA);
        const int wg = blk - 254;          // 0..127
        const int b = wg >> 2, half = (wg >> 1) & 1, it = wg & 1;
        const float* WA  = (half ? w3 : w1) + (size_t)it * NHID * ND;
        const float* inp = inputs + (size_t)b * NN * ND;
        ushort* dst = iwa + (size_t)wg * NHID * NN;    // [h][n]

        const int lane = t & 63, wave = t >> 6;
        const int l16 = lane & 15, l4 = lane >> 4;

        for (int hh = 0; hh < 2; ++hh) {
            const int ht = wave * 2 + hh;
            s16x8 bf[2];
#pragma unroll
            for (int ks = 0; ks < 2; ++ks) {
                const float* p = WA + (size_t)(ht * 16 + l16) * ND + ks * 32 + l4 * 8;
                float4 u = ldg4(p), v = ldg4(p + 4);
                s16x8 f;
                f[0] = (short)f2bf(u.x); f[1] = (short)f2bf(u.y);
                f[2] = (short)f2bf(u.z); f[3] = (short)f2bf(u.w);
                f[4] = (short)f2bf(v.x); f[5] = (short)f2bf(v.y);
                f[6] = (short)f2bf(v.z); f[7] = (short)f2bf(v.w);
                bf[ks] = f;
            }
            for (int nt = 0; nt < 8; ++nt) {
                s16x8 af[2];
#pragma unroll
                for (int ks = 0; ks < 2; ++ks) {
                    const float* p = inp + (size_t)(nt * 16 + l16) * ND + ks * 32 + l4 * 8;
                    float4 u = ldg4(p), v = ldg4(p + 4);
                    s16x8 f;
                    f[0] = (short)f2bf(u.x); f[1] = (short)f2bf(u.y);
                    f[2] = (short)f2bf(u.z); f[3] = (short)f2bf(u.w);
                    f[4] = (short)f2bf(v.x); f[5] = (short)f2bf(v.y);
                    f[6] = (short)f2bf(v.z); f[7] = (short)f2bf(v.w);
                    af[ks] = f;
                }
                f32x4 c = (f32x4){0.f, 0.f, 0.f, 0.f};
                c = MFMA16(af[0], bf[0], c);
                c = MFMA16(af[1], bf[1], c);
                s16x4 o;
                o[0] = (short)f2bf(c[0]); o[1] = (short)f2bf(c[1]);
                o[2] = (short)f2bf(c[2]); o[3] = (short)f2bf(c[3]);
                *(s16x4*)&dst[(size_t)(ht * 16 + l16) * NN + nt * 16 + l4 * 4] = o;
            }
        }
    }
}

// ---------------------------------------------------------------------------
// k_edge: H = relu(RS@inpWA + bA); M = sum_it relu(H@WB^T + bB)*rt;
//         agg += rrT@M.  grid 512 = b*16 + half*8 + chunk, block 512 (8 waves).
// NOTE: __launch_bounds__ 2nd arg is CUDA-semantics min BLOCKS/CU on this
// toolchain (measured: (512,4)->VGPR 64 + spills, (512,2)->VGPR 128 clean).
// (512,2) => 128-VGPR cap, 2 blocks/CU co-resident (LDS 66.5KB*2 <= 160KB).
// ---------------------------------------------------------------------------
__global__ __launch_bounds__(512, 2)
void k_edge(const float* __restrict__ rel_type, const int* __restrict__ indices,
            const float* __restrict__ b1, const float* __restrict__ b2,
            const float* __restrict__ b3, const float* __restrict__ b4,
            const float* __restrict__ w2, const float* __restrict__ w4,
            char* __restrict__ ws)
{
    const ushort* rs  = (const ushort*)(ws + WS_RS);
    const ushort* rrT = (const ushort*)(ws + WS_RRT);
    const ushort* iwa = (const ushort*)(ws + WS_IWA);
    ushort* partial   = (ushort*)ws;

    const int tid  = threadIdx.x;
    const int wave = tid >> 6;
    const int lane = tid & 63;
    const int l16  = lane & 15;
    const int l4   = lane >> 4;

    const int wg    = blockIdx.x;
    const int b     = wg >> 4;
    const int half  = (wg >> 3) & 1;
    const int chunk = wg & 7;

    const float* BA    = half ? b3 : b1;
    const float* BB    = half ? b4 : b2;
    const float* WBsrc = half ? w4 : w2;

    __shared__ ushort H_s[2][64 * 128];   // 32 KB, rows 256B (e-major, per it)
    __shared__ ushort Mt_s[128 * 64];     // 16 KB, rows 128B (m-major)
    __shared__ ushort rr_s[128 * 64];     // 16 KB, rows 128B (n-major)
    __shared__ int    idx_s[64];
    __shared__ float  rt_s[128];

    // persistent B-fragments (96 VGPRs: wIW 32 + wB 32 + agg 32)
    s16x8 wIW[2][4];   // inpWA [it][ks]: lane col h = wave*16+l16, k = n
    const ushort* iwb = iwa + (size_t)((b * 2 + half) * 2) * NHID * NN;
#pragma unroll
    for (int it = 0; it < 2; ++it)
#pragma unroll
        for (int ks = 0; ks < 4; ++ks)
            wIW[it][ks] = *(const s16x8*)(iwb + (size_t)it * NHID * NN +
                                          (size_t)(wave * 16 + l16) * NN + ks * 32 + l4 * 8);
    s16x8 wB[2][4];    // WB [it][ks]: lane col m = wave*16+l16, k = h (cvt from f32)
#pragma unroll
    for (int it = 0; it < 2; ++it)
#pragma unroll
        for (int ks = 0; ks < 4; ++ks) {
            const float* p = WBsrc + (size_t)(it * NM + wave * 16 + l16) * NHID + ks * 32 + l4 * 8;
            float4 u = ldg4(p), v = ldg4(p + 4);
            s16x8 f;
            f[0] = (short)f2bf(u.x); f[1] = (short)f2bf(u.y);
            f[2] = (short)f2bf(u.z); f[3] = (short)f2bf(u.w);
            f[4] = (short)f2bf(v.x); f[5] = (short)f2bf(v.y);
            f[6] = (short)f2bf(v.z); f[7] = (short)f2bf(v.w);
            wB[it][ks] = f;
        }
    float biasA[2] = {BA[wave * 16 + l16], BA[NHID + wave * 16 + l16]};
    float biasB[2] = {BB[wave * 16 + l16], BB[NM + wave * 16 + l16]};

    f32x4 agg[8];
#pragma unroll
    for (int r = 0; r < 8; ++r) agg[r] = (f32x4){0.f, 0.f, 0.f, 0.f};

    const int t0 = chunk * 16;
    const int t1 = (t0 + 16 < NTILE) ? (t0 + 16) : NTILE;

    for (int tile = t0; tile < t1; ++tile) {
        const int e_base = tile * TILE_E;
        __syncthreads();                                   // (A)
        if (tid < 64) {
            idx_s[tid] = indices[half * EHALF + e_base + tid];
        } else if (tid < 192) {
            int q = tid - 64, e = q >> 1, it = q & 1;
            int eg = indices[half * EHALF + e_base + e];
            rt_s[q] = rel_type[((size_t)b * NE + eg) * NT + it];
        }
        __syncthreads();                                   // (B)

        // stage rr_s (consumed in agg, after (D))
        const int eg0 = idx_s[0];
        for (int i = tid; i < 1024; i += 512) {
            int n = i >> 3, c = i & 7;
            s16x8 v = *(const s16x8*)(rrT + (size_t)n * NE + eg0 + c * 8);
            *(s16x8*)swz(rr_s, n, 128, c * 16) = v;
        }

        // ---- H phase: H[it] = relu(RS @ inpWA[it] + bA[it]) ----
        for (int et = 0; et < 4; ++et) {
            const int erow = et * 16 + l16;
            const ushort* arow = rs + (size_t)idx_s[erow] * 128 + l4 * 8;
            s16x8 a0 = *(const s16x8*)(arow);
            s16x8 a1 = *(const s16x8*)(arow + 32);
            s16x8 a2 = *(const s16x8*)(arow + 64);
            s16x8 a3 = *(const s16x8*)(arow + 96);
#pragma unroll
            for (int it = 0; it < 2; ++it) {
                f32x4 c = (f32x4){0.f, 0.f, 0.f, 0.f};
                __builtin_amdgcn_s_setprio(1);
                c = MFMA16(a0, wIW[it][0], c);
                c = MFMA16(a1, wIW[it][1], c);
                c = MFMA16(a2, wIW[it][2], c);
                c = MFMA16(a3, wIW[it][3], c);
                __builtin_amdgcn_s_setprio(0);
#pragma unroll
                for (int r = 0; r < 4; ++r) {
                    int er = et * 16 + l4 * 4 + r;
                    *(ushort*)swz(&H_s[it][0], er, 256, (wave * 16 + l16) * 2) =
                        f2bf(fmaxf(c[r] + biasA[it], 0.f));
                }
            }
        }
        __syncthreads();                                   // (C)

        // ---- M phase: msg = sum_it relu(H[it] @ WB[it]^T + bB[it]) * rt ----
        float msg_acc[4][4];
#pragma unroll
        for (int et = 0; et < 4; ++et)
#pragma unroll
            for (int r = 0; r < 4; ++r) msg_acc[et][r] = 0.f;

        for (int et = 0; et < 4; ++et) {
            const int e = et * 16 + l16;
#pragma unroll
            for (int it = 0; it < 2; ++it) {
                f32x4 c = (f32x4){0.f, 0.f, 0.f, 0.f};
                __builtin_amdgcn_s_setprio(1);
#pragma unroll
                for (int ks = 0; ks < 4; ++ks) {
                    s16x8 a = *(const s16x8*)swzc(&H_s[it][0], e, 256, (ks * 32 + l4 * 8) * 2);
                    c = MFMA16(a, wB[it][ks], c);
                }
                __builtin_amdgcn_s_setprio(0);
#pragma unroll
                for (int r = 0; r < 4; ++r) {
                    int er = et * 16 + l4 * 4 + r;
                    msg_acc[et][r] += fmaxf(c[r] + biasB[it], 0.f) * rt_s[er * 2 + it];
                }
            }
        }
        // write Mt (m-major)
        {
            const int m = wave * 16 + l16;
#pragma unroll
            for (int et = 0; et < 4; ++et) {
                s16x4 v;
                v[0] = (short)f2bf(msg_acc[et][0]);
                v[1] = (short)f2bf(msg_acc[et][1]);
                v[2] = (short)f2bf(msg_acc[et][2]);
                v[3] = (short)f2bf(msg_acc[et][3]);
                *(s16x4*)swz(Mt_s, m, 128, (et * 16 + l4 * 4) * 2) = v;
            }
        }
        __syncthreads();                                   // (D)

        // ---- agg += rrT @ msg ----
        {
            const int m = wave * 16 + l16;
            s16x8 bb0 = *(const s16x8*)swzc(Mt_s, m, 128, (l4 * 8) * 2);
            s16x8 bb1 = *(const s16x8*)swzc(Mt_s, m, 128, (32 + l4 * 8) * 2);
            __builtin_amdgcn_s_setprio(1);
#pragma unroll
            for (int nt = 0; nt < 8; ++nt) {
                int n = nt * 16 + l16;
                s16x8 a0 = *(const s16x8*)swzc(rr_s, n, 128, (l4 * 8) * 2);
                s16x8 a1 = *(const s16x8*)swzc(rr_s, n, 128, (32 + l4 * 8) * 2);
                agg[nt] = MFMA16(a0, bb0, agg[nt]);
                agg[nt] = MFMA16(a1, bb1, agg[nt]);
            }
            __builtin_amdgcn_s_setprio(0);
        }
    }

    // store bf16 partialT [wg][m][n] (vector s16x4)
    {
        ushort* dst = partial + (size_t)wg * (NN * NM);
        const int m = wave * 16 + l16;
#pragma unroll
        for (int nt = 0; nt < 8; ++nt) {
            s16x4 v;
            v[0] = (short)f2bf(agg[nt][0]);
            v[1] = (short)f2bf(agg[nt][1]);
            v[2] = (short)f2bf(agg[nt][2]);
            v[3] = (short)f2bf(agg[nt][3]);
            *(s16x4*)&dst[(size_t)m * NN + nt * 16 + l4 * 4] = v;
        }
    }
}

// ---------------------------------------------------------------------------
// k_out: reduce 16 bf16 partials -> node MLP 128->256->256->64 + residual
// ---------------------------------------------------------------------------
__global__ __launch_bounds__(256)
void k_out(const ushort* __restrict__ partial,
           const float* __restrict__ inputs,
           const float* __restrict__ ow1, const float* __restrict__ ob1,
           const float* __restrict__ ow2, const float* __restrict__ ob2,
           const float* __restrict__ ow3, const float* __restrict__ ob3,
           float* __restrict__ out)
{
    const int t  = threadIdx.x;
    const int wg = blockIdx.x;      // 0..255
    const int b  = wg >> 3;
    const int n0 = (wg & 7) * 16;

    __shared__ float xr[16 * NM];
    __shared__ float h1[16 * NOH];
    __shared__ float h2[16 * NOH];

    // reduce 16 partials (transposed layout [m][n])
    for (int u = t; u < 512; u += 256) {
        const int m = u >> 2, g = u & 3;
        float s0 = 0.f, s1 = 0.f, s2 = 0.f, s3 = 0.f;
#pragma unroll
        for (int c = 0; c < 16; ++c) {
            const ushort* p = partial + ((size_t)(b * 16 + c)) * (NN * NM) +
                              (size_t)m * NN + n0 + g * 4;
            s16x4 v = *(const s16x4*)p;
            s0 += bf2f((ushort)v[0]); s1 += bf2f((ushort)v[1]);
            s2 += bf2f((ushort)v[2]); s3 += bf2f((ushort)v[3]);
        }
        xr[(g * 4 + 0) * NM + m] = s0;
        xr[(g * 4 + 1) * NM + m] = s1;
        xr[(g * 4 + 2) * NM + m] = s2;
        xr[(g * 4 + 3) * NM + m] = s3;
    }
    __syncthreads();

    {
        float acc[16];
        const float bias = ob1[t];
#pragma unroll
        for (int r = 0; r < 16; ++r) acc[r] = bias;
        const float* wrow = ow1 + (size_t)t * NM;
#pragma unroll 2
        for (int mq = 0; mq < NM / 4; ++mq) {
            const float4 w = ldg4(wrow + mq * 4);
#pragma unroll
            for (int r = 0; r < 16; ++r) {
                const float4 xv = *reinterpret_cast<const float4*>(&xr[r * NM + mq * 4]);
                acc[r] += xv.x * w.x + xv.y * w.y + xv.z * w.z + xv.w * w.w;
            }
        }
#pragma unroll
        for (int r = 0; r < 16; ++r) h1[r * NOH + t] = fmaxf(acc[r], 0.f);
    }
    __syncthreads();

    {
        float acc[16];
        const float bias = ob2[t];
#pragma unroll
        for (int r = 0; r < 16; ++r) acc[r] = bias;
        const float* wrow = ow2 + (size_t)t * NOH;
#pragma unroll 2
        for (int hq = 0; hq < NOH / 4; ++hq) {
            const float4 w = ldg4(wrow + hq * 4);
#pragma unroll
            for (int r = 0; r < 16; ++r) {
                const float4 hv = *reinterpret_cast<const float4*>(&h1[r * NOH + hq * 4]);
                acc[r] += hv.x * w.x + hv.y * w.y + hv.z * w.z + hv.w * w.w;
            }
        }
#pragma unroll
        for (int r = 0; r < 16; ++r) h2[r * NOH + t] = fmaxf(acc[r], 0.f);
    }
    __syncthreads();

    {
        const int d  = t & 63;
        const int rg = t >> 6;
        float acc[4] = {0.f, 0.f, 0.f, 0.f};
        const float* wrow = ow3 + (size_t)d * NOH;
#pragma unroll 2
        for (int hq = 0; hq < NOH / 4; ++hq) {
            const float4 w = ldg4(wrow + hq * 4);
#pragma unroll
            for (int r = 0; r < 4; ++r) {
                const float4 hv = *reinterpret_cast<const float4*>(&h2[(rg * 4 + r) * NOH + hq * 4]);
                acc[r] += hv.x * w.x + hv.y * w.y + hv.z * w.z + hv.w * w.w;
            }
        }
        const float bias = ob3[d];
#pragma unroll
        for (int r = 0; r < 4; ++r) {
            const int n = n0 + rg * 4 + r;
            const size_t idx = ((size_t)b * NN + n) * ND + d;
            out[idx] = inputs[idx] + acc[r] + bias;
        }
    }
}

extern "C" void kernel_launch(void* const* d_in, const int* in_sizes, int n_in,
                              void* d_out, int out_size, void* d_ws, size_t ws_size,
                              hipStream_t stream)
{
    const float* inputs   = (const float*)d_in[0];
    const float* rel_rec  = (const float*)d_in[1];
    const float* rel_send = (const float*)d_in[2];
    const float* rel_type = (const float*)d_in[3];
    const int*   indices  = (const int*)  d_in[4];
    const float* w1  = (const float*)d_in[5];
    const float* b1  = (const float*)d_in[6];
    const float* w2  = (const float*)d_in[7];
    const float* b2  = (const float*)d_in[8];
    const float* w3  = (const float*)d_in[9];
    const float* b3  = (const float*)d_in[10];
    const float* w4  = (const float*)d_in[11];
    const float* b4  = (const float*)d_in[12];
    const float* ow1 = (const float*)d_in[13];
    const float* ob1 = (const float*)d_in[14];
    const float* ow2 = (const float*)d_in[15];
    const float* ob2 = (const float*)d_in[16];
    const float* ow3 = (const float*)d_in[17];
    const float* ob3 = (const float*)d_in[18];

    char* ws = (char*)d_ws;

    k_pre <<<dim3(382), dim3(256), 0, stream>>>(inputs, rel_rec, rel_send,
                                                w1, w3, ws);
    k_edge<<<dim3(512), dim3(512), 0, stream>>>(rel_type, indices,
                                                b1, b2, b3, b4, w2, w4, ws);
    k_out <<<dim3(256), dim3(256), 0, stream>>>((const ushort*)ws, inputs,
                                                ow1, ob1, ow2, ob2, ow3, ob3,
                                                (float*)d_out);
}

// Round 5
// 198.207 us; speedup vs baseline: 1.9704x; 1.5497x over previous
//
#include <hip/hip_runtime.h>
#include <hip/hip_bf16.h>

#define NB 32
#define NN 128
#define NE 16256
#define ND 64
#define NHID 128
#define NM 128
#define NOH 256
#define NT 2
#define EHALF 8128
#define NTILE 127        // 64-edge tiles per half (127*64 == 8128 exactly)
#define TILE_E 64

typedef short s16x8 __attribute__((ext_vector_type(8)));
typedef short s16x4 __attribute__((ext_vector_type(4)));
typedef float f32x4 __attribute__((ext_vector_type(4)));

#define MFMA16(a, b, c) __builtin_amdgcn_mfma_f32_16x16x32_bf16((a), (b), (c), 0, 0, 0)

// ---- ws layout (bytes) ----
// partial: bf16 [256][m=128][n=128]
#define PARTIAL_SZ ((size_t)256 * 128 * 128 * 2)          //  8,388,608
#define WS_RS      (PARTIAL_SZ)                           // ushort[NE][128]
#define RS_SZ      ((size_t)NE * 128 * 2)                 //  4,161,536
#define WS_RRT     (WS_RS + RS_SZ)                        // ushort[128][NE]
#define RRT_SZ     ((size_t)128 * NE * 2)                 //  4,161,536
#define WS_IWA     (WS_RRT + RRT_SZ)                      // ushort[b][half][it][h=128][n=128]
#define IWA_SZ     ((size_t)NB * 2 * 2 * 128 * 128 * 2)   //  8,388,608
// total = 25.1 MB (<= proven 32 MB)

__device__ __forceinline__ ushort f2bf(float x) {
    uint u = __float_as_uint(x);
    return (ushort)((u + 0x7fffu + ((u >> 16) & 1u)) >> 16);
}
__device__ __forceinline__ float bf2f(ushort h) {
    return __uint_as_float(((uint)h) << 16);
}
__device__ __forceinline__ float4 ldg4(const float* p) {
    return *reinterpret_cast<const float4*>(p);
}
// XOR-swizzle within a row (G4): byte ^= (row&7)<<4
__device__ __forceinline__ char* swz(void* base, int row, int rowBytes, int bir) {
    return (char*)base + row * rowBytes + (bir ^ ((row & 7) << 4));
}
__device__ __forceinline__ const char* swzc(const void* base, int row, int rowBytes, int bir) {
    return (const char*)base + row * rowBytes + (bir ^ ((row & 7) << 4));
}

// ---------------------------------------------------------------------------
// k_pre: fused conversions + inpWA precompute.
// blocks 0..126: rrT transpose+convert; 127..253: rs convert;
// blocks 254..381: inpWA[b][half][it] = (inp[b] @ WA^T) in bf16 [h][n]
// ---------------------------------------------------------------------------
__global__ __launch_bounds__(256)
void k_pre(const float* __restrict__ inputs,
           const float* __restrict__ rel_rec, const float* __restrict__ rel_send,
           const float* __restrict__ w1, const float* __restrict__ w3,
           char* __restrict__ ws)
{
    ushort* rs  = (ushort*)(ws + WS_RS);
    ushort* rrT = (ushort*)(ws + WS_RRT);
    const int t = threadIdx.x;
    const int blk = blockIdx.x;
    __shared__ float lds[128][65];

    if (blk < 127) {                       // rrT: transpose rel_rec -> [n][e] bf16
        const int eb = blk;
        for (int nh = 0; nh < 2; ++nh) {
            __syncthreads();
            for (int i = t; i < 128 * 64; i += 256) {
                int e = i >> 6, n = i & 63;
                lds[e][n] = rel_rec[(size_t)(eb * 128 + e) * 128 + nh * 64 + n];
            }
            __syncthreads();
            for (int i = t; i < 64 * 128; i += 256) {
                int n = i >> 7, e = i & 127;
                rrT[(size_t)(nh * 64 + n) * NE + eb * 128 + e] = f2bf(lds[e][n]);
            }
        }
    } else if (blk < 254) {                // rs: straight convert
        const int eb = blk - 127;
        const float4* src = (const float4*)(rel_send + (size_t)eb * 16384);
        for (int i = t; i < 4096; i += 256) {
            float4 v = src[i];
            ushort4 o;
            o.x = f2bf(v.x); o.y = f2bf(v.y); o.z = f2bf(v.z); o.w = f2bf(v.w);
            *(ushort4*)(rs + (size_t)eb * 16384 + (size_t)i * 4) = o;
        }
    } else {                               // inpWA precompute (MFMA)
        ushort* iwa = (ushort*)(ws + WS_IWA);
        const int wg = blk - 254;          // 0..127
        const int b = wg >> 2, half = (wg >> 1) & 1, it = wg & 1;
        const float* WA  = (half ? w3 : w1) + (size_t)it * NHID * ND;
        const float* inp = inputs + (size_t)b * NN * ND;
        ushort* dst = iwa + (size_t)wg * NHID * NN;    // [h][n]

        const int lane = t & 63, wave = t >> 6;
        const int l16 = lane & 15, l4 = lane >> 4;

        for (int hh = 0; hh < 2; ++hh) {
            const int ht = wave * 2 + hh;
            s16x8 bf[2];
#pragma unroll
            for (int ks = 0; ks < 2; ++ks) {
                const float* p = WA + (size_t)(ht * 16 + l16) * ND + ks * 32 + l4 * 8;
                float4 u = ldg4(p), v = ldg4(p + 4);
                s16x8 f;
                f[0] = (short)f2bf(u.x); f[1] = (short)f2bf(u.y);
                f[2] = (short)f2bf(u.z); f[3] = (short)f2bf(u.w);
                f[4] = (short)f2bf(v.x); f[5] = (short)f2bf(v.y);
                f[6] = (short)f2bf(v.z); f[7] = (short)f2bf(v.w);
                bf[ks] = f;
            }
            for (int nt = 0; nt < 8; ++nt) {
                s16x8 af[2];
#pragma unroll
                for (int ks = 0; ks < 2; ++ks) {
                    const float* p = inp + (size_t)(nt * 16 + l16) * ND + ks * 32 + l4 * 8;
                    float4 u = ldg4(p), v = ldg4(p + 4);
                    s16x8 f;
                    f[0] = (short)f2bf(u.x); f[1] = (short)f2bf(u.y);
                    f[2] = (short)f2bf(u.z); f[3] = (short)f2bf(u.w);
                    f[4] = (short)f2bf(v.x); f[5] = (short)f2bf(v.y);
                    f[6] = (short)f2bf(v.z); f[7] = (short)f2bf(v.w);
                    af[ks] = f;
                }
                f32x4 c = (f32x4){0.f, 0.f, 0.f, 0.f};
                c = MFMA16(af[0], bf[0], c);
                c = MFMA16(af[1], bf[1], c);
                s16x4 o;
                o[0] = (short)f2bf(c[0]); o[1] = (short)f2bf(c[1]);
                o[2] = (short)f2bf(c[2]); o[3] = (short)f2bf(c[3]);
                *(s16x4*)&dst[(size_t)(ht * 16 + l16) * NN + nt * 16 + l4 * 4] = o;
            }
        }
    }
}

// ---------------------------------------------------------------------------
// k_edge: grid 256 = b*8 + half*4 + chunk(4). block 512 (8 waves), 1 block/CU.
// ONE barrier per 64-edge tile:
//   P_t: stage idx/rt/rs(t+1)/rr(t) + H[t] -> H_s[buf]        | barrier
//   Q_t: M[t] from H_s[buf] (+rt scale), Mt wave-private LDS roundtrip
//        (no barrier - producer wave == consumer wave), agg += rrT@M
// H_s/rs_s/rr_s/idx/rt double-buffered so Q_t and P_{t+1} share a segment.
// __launch_bounds__ 2nd arg = min BLOCKS/CU on this toolchain (measured).
// ---------------------------------------------------------------------------
__global__ __launch_bounds__(512, 1)
void k_edge(const float* __restrict__ rel_type, const int* __restrict__ indices,
            const float* __restrict__ b1, const float* __restrict__ b2,
            const float* __restrict__ b3, const float* __restrict__ b4,
            const float* __restrict__ w2, const float* __restrict__ w4,
            char* __restrict__ ws)
{
    const ushort* rs  = (const ushort*)(ws + WS_RS);
    const ushort* rrT = (const ushort*)(ws + WS_RRT);
    const ushort* iwa = (const ushort*)(ws + WS_IWA);
    ushort* partial   = (ushort*)ws;

    const int tid  = threadIdx.x;
    const int wave = tid >> 6;
    const int lane = tid & 63;
    const int l16  = lane & 15;
    const int l4   = lane >> 4;

    const int wg    = blockIdx.x;
    const int b     = wg >> 3;
    const int half  = (wg >> 2) & 1;
    const int chunk = wg & 3;

    const float* BA    = half ? b3 : b1;
    const float* BB    = half ? b4 : b2;
    const float* WBsrc = half ? w4 : w2;

    __shared__ ushort H_s[2][2][64 * 128];  // 64 KB (buf, it)
    __shared__ ushort rs_s[2][64 * 128];    // 32 KB (rows 256B)
    __shared__ ushort rr_s[2][128 * 64];    // 32 KB (rows 128B)
    __shared__ ushort Mt_s[128 * 64];       // 16 KB (wave-private rows)
    __shared__ int    idx_s[2][64];
    __shared__ float  rt_s[2][128];

    // persistent B-fragments
    s16x8 wIW[2][4];
    const ushort* iwb = iwa + (size_t)((b * 2 + half) * 2) * NHID * NN;
#pragma unroll
    for (int it = 0; it < 2; ++it)
#pragma unroll
        for (int ks = 0; ks < 4; ++ks)
            wIW[it][ks] = *(const s16x8*)(iwb + (size_t)it * NHID * NN +
                                          (size_t)(wave * 16 + l16) * NN + ks * 32 + l4 * 8);
    s16x8 wB[2][4];
#pragma unroll
    for (int it = 0; it < 2; ++it)
#pragma unroll
        for (int ks = 0; ks < 4; ++ks) {
            const float* p = WBsrc + (size_t)(it * NM + wave * 16 + l16) * NHID + ks * 32 + l4 * 8;
            float4 u = ldg4(p), v = ldg4(p + 4);
            s16x8 f;
            f[0] = (short)f2bf(u.x); f[1] = (short)f2bf(u.y);
            f[2] = (short)f2bf(u.z); f[3] = (short)f2bf(u.w);
            f[4] = (short)f2bf(v.x); f[5] = (short)f2bf(v.y);
            f[6] = (short)f2bf(v.z); f[7] = (short)f2bf(v.w);
            wB[it][ks] = f;
        }
    float biasA[2] = {BA[wave * 16 + l16], BA[NHID + wave * 16 + l16]};
    float biasB[2] = {BB[wave * 16 + l16], BB[NM + wave * 16 + l16]};

    f32x4 agg[8];
#pragma unroll
    for (int r = 0; r < 8; ++r) agg[r] = (f32x4){0.f, 0.f, 0.f, 0.f};

    const int t0 = chunk * 32;
    const int t1 = (t0 + 32 < NTILE) ? (t0 + 32) : NTILE;

    // ---- prologue: stage idx + rs for tile t0 into buf 0 ----
    {
        const int base0 = half * EHALF + t0 * TILE_E;
        if (tid < 64) idx_s[0][tid] = indices[base0 + tid];
#pragma unroll
        for (int s = 0; s < 2; ++s) {
            const int i = tid + s * 512;
            const int e = i >> 4, c = i & 15;
            const int eid = indices[base0 + e];
            s16x8 v = *(const s16x8*)(rs + (size_t)eid * 128 + c * 8);
            *(s16x8*)swz(&rs_s[0][0], e, 256, c * 16) = v;
        }
    }
    __syncthreads();

    for (int t = t0; t < t1; ++t) {
        const int buf  = (t - t0) & 1;
        const int nbuf = buf ^ 1;
        const bool do_next = (t + 1) < NTILE;
        const int base_next = half * EHALF + (t + 1) * TILE_E;

        // (a) rr staging loads for tile t (columns eg0.. : contiguous-id slice)
        const int eg0 = idx_s[buf][0];
        s16x8 rrv0, rrv1;
        const int rn0 = tid >> 3, rc0 = tid & 7;
        const int rn1 = (tid + 512) >> 3, rc1 = (tid + 512) & 7;
        rrv0 = *(const s16x8*)(rrT + (size_t)rn0 * NE + eg0 + rc0 * 8);
        rrv1 = *(const s16x8*)(rrT + (size_t)rn1 * NE + eg0 + rc1 * 8);

        // (b) rs staging loads for tile t+1
        s16x8 rsv0, rsv1;
        const int se0 = tid >> 4, sc0 = tid & 15;
        const int se1 = (tid + 512) >> 4, sc1 = (tid + 512) & 15;
        if (do_next) {
            const int eid0 = indices[base_next + se0];
            const int eid1 = indices[base_next + se1];
            rsv0 = *(const s16x8*)(rs + (size_t)eid0 * 128 + sc0 * 8);
            rsv1 = *(const s16x8*)(rs + (size_t)eid1 * 128 + sc1 * 8);
        }

        // (c) idx stage for tile t+1
        if (do_next && tid < 64) idx_s[nbuf][tid] = indices[base_next + tid];

        // (d) rt stage for tile t
        if (tid < 128) {
            const int e = tid >> 1, it = tid & 1;
            const int eg = idx_s[buf][e];
            rt_s[buf][tid] = rel_type[((size_t)b * NE + eg) * NT + it];
        }

        // (e) H phase: H[it] = relu(RS @ inpWA[it] + bA[it]) -> H_s[buf]
#pragma unroll
        for (int et = 0; et < 4; ++et) {
            const int erow = et * 16 + l16;
            s16x8 a0 = *(const s16x8*)swzc(&rs_s[buf][0], erow, 256, (0 * 32 + l4 * 8) * 2);
            s16x8 a1 = *(const s16x8*)swzc(&rs_s[buf][0], erow, 256, (1 * 32 + l4 * 8) * 2);
            s16x8 a2 = *(const s16x8*)swzc(&rs_s[buf][0], erow, 256, (2 * 32 + l4 * 8) * 2);
            s16x8 a3 = *(const s16x8*)swzc(&rs_s[buf][0], erow, 256, (3 * 32 + l4 * 8) * 2);
#pragma unroll
            for (int it = 0; it < 2; ++it) {
                f32x4 c = (f32x4){0.f, 0.f, 0.f, 0.f};
                __builtin_amdgcn_s_setprio(1);
                c = MFMA16(a0, wIW[it][0], c);
                c = MFMA16(a1, wIW[it][1], c);
                c = MFMA16(a2, wIW[it][2], c);
                c = MFMA16(a3, wIW[it][3], c);
                __builtin_amdgcn_s_setprio(0);
#pragma unroll
                for (int r = 0; r < 4; ++r) {
                    const int er = et * 16 + l4 * 4 + r;
                    *(ushort*)swz(&H_s[buf][it][0], er, 256, (wave * 16 + l16) * 2) =
                        f2bf(fmaxf(c[r] + biasA[it], 0.f));
                }
            }
        }

        // (f) LDS staging writes (vmcnt waits land here, covered by H work)
        *(s16x8*)swz(&rr_s[buf][0], rn0, 128, rc0 * 16) = rrv0;
        *(s16x8*)swz(&rr_s[buf][0], rn1, 128, rc1 * 16) = rrv1;
        if (do_next) {
            *(s16x8*)swz(&rs_s[nbuf][0], se0, 256, sc0 * 16) = rsv0;
            *(s16x8*)swz(&rs_s[nbuf][0], se1, 256, sc1 * 16) = rsv1;
        }
        __syncthreads();                                   // the ONE barrier

        // ---- Q phase: M then agg ----
        float macc[4][4];
#pragma unroll
        for (int et = 0; et < 4; ++et)
#pragma unroll
            for (int r = 0; r < 4; ++r) macc[et][r] = 0.f;

#pragma unroll
        for (int et = 0; et < 4; ++et) {
            const int e = et * 16 + l16;
            float2 rtv[4];
#pragma unroll
            for (int r = 0; r < 4; ++r)
                rtv[r] = *(const float2*)&rt_s[buf][(et * 16 + l4 * 4 + r) * 2];
#pragma unroll
            for (int it = 0; it < 2; ++it) {
                f32x4 c = (f32x4){0.f, 0.f, 0.f, 0.f};
                __builtin_amdgcn_s_setprio(1);
#pragma unroll
                for (int ks = 0; ks < 4; ++ks) {
                    s16x8 a = *(const s16x8*)swzc(&H_s[buf][it][0], e, 256, (ks * 32 + l4 * 8) * 2);
                    c = MFMA16(a, wB[it][ks], c);
                }
                __builtin_amdgcn_s_setprio(0);
#pragma unroll
                for (int r = 0; r < 4; ++r)
                    macc[et][r] += fmaxf(c[r] + biasB[it], 0.f) * (it ? rtv[r].y : rtv[r].x);
            }
        }

        // Mt: wave-private LDS roundtrip (wave w touches only rows 16w..16w+15)
        {
            const int m = wave * 16 + l16;
#pragma unroll
            for (int et = 0; et < 4; ++et) {
                s16x4 v;
                v[0] = (short)f2bf(macc[et][0]);
                v[1] = (short)f2bf(macc[et][1]);
                v[2] = (short)f2bf(macc[et][2]);
                v[3] = (short)f2bf(macc[et][3]);
                *(s16x4*)swz(Mt_s, m, 128, (et * 16 + l4 * 4) * 2) = v;
            }
            s16x8 bb0 = *(const s16x8*)swzc(Mt_s, m, 128, (l4 * 8) * 2);
            s16x8 bb1 = *(const s16x8*)swzc(Mt_s, m, 128, (32 + l4 * 8) * 2);
            __builtin_amdgcn_s_setprio(1);
#pragma unroll
            for (int nt = 0; nt < 8; ++nt) {
                const int n = nt * 16 + l16;
                s16x8 a0 = *(const s16x8*)swzc(&rr_s[buf][0], n, 128, (l4 * 8) * 2);
                s16x8 a1 = *(const s16x8*)swzc(&rr_s[buf][0], n, 128, (32 + l4 * 8) * 2);
                agg[nt] = MFMA16(a0, bb0, agg[nt]);
                agg[nt] = MFMA16(a1, bb1, agg[nt]);
            }
            __builtin_amdgcn_s_setprio(0);
        }
    }

    // store bf16 partialT [wg][m][n] (vector s16x4)
    {
        ushort* dst = partial + (size_t)wg * (NN * NM);
        const int m = wave * 16 + l16;
#pragma unroll
        for (int nt = 0; nt < 8; ++nt) {
            s16x4 v;
            v[0] = (short)f2bf(agg[nt][0]);
            v[1] = (short)f2bf(agg[nt][1]);
            v[2] = (short)f2bf(agg[nt][2]);
            v[3] = (short)f2bf(agg[nt][3]);
            *(s16x4*)&dst[(size_t)m * NN + nt * 16 + l4 * 4] = v;
        }
    }
}

// ---------------------------------------------------------------------------
// k_out: reduce 8 bf16 partials -> node MLP 128->256->256->64 + residual
// ---------------------------------------------------------------------------
__global__ __launch_bounds__(256)
void k_out(const ushort* __restrict__ partial,
           const float* __restrict__ inputs,
           const float* __restrict__ ow1, const float* __restrict__ ob1,
           const float* __restrict__ ow2, const float* __restrict__ ob2,
           const float* __restrict__ ow3, const float* __restrict__ ob3,
           float* __restrict__ out)
{
    const int t  = threadIdx.x;
    const int wg = blockIdx.x;      // 0..255
    const int b  = wg >> 3;
    const int n0 = (wg & 7) * 16;

    __shared__ float xr[16 * NM];
    __shared__ float h1[16 * NOH];
    __shared__ float h2[16 * NOH];

    // reduce 8 partials (transposed layout [m][n])
    for (int u = t; u < 512; u += 256) {
        const int m = u >> 2, g = u & 3;
        float s0 = 0.f, s1 = 0.f, s2 = 0.f, s3 = 0.f;
#pragma unroll
        for (int c = 0; c < 8; ++c) {
            const ushort* p = partial + ((size_t)(b * 8 + c)) * (NN * NM) +
                              (size_t)m * NN + n0 + g * 4;
            s16x4 v = *(const s16x4*)p;
            s0 += bf2f((ushort)v[0]); s1 += bf2f((ushort)v[1]);
            s2 += bf2f((ushort)v[2]); s3 += bf2f((ushort)v[3]);
        }
        xr[(g * 4 + 0) * NM + m] = s0;
        xr[(g * 4 + 1) * NM + m] = s1;
        xr[(g * 4 + 2) * NM + m] = s2;
        xr[(g * 4 + 3) * NM + m] = s3;
    }
    __syncthreads();

    {
        float acc[16];
        const float bias = ob1[t];
#pragma unroll
        for (int r = 0; r < 16; ++r) acc[r] = bias;
        const float* wrow = ow1 + (size_t)t * NM;
#pragma unroll 2
        for (int mq = 0; mq < NM / 4; ++mq) {
            const float4 w = ldg4(wrow + mq * 4);
#pragma unroll
            for (int r = 0; r < 16; ++r) {
                const float4 xv = *reinterpret_cast<const float4*>(&xr[r * NM + mq * 4]);
                acc[r] += xv.x * w.x + xv.y * w.y + xv.z * w.z + xv.w * w.w;
            }
        }
#pragma unroll
        for (int r = 0; r < 16; ++r) h1[r * NOH + t] = fmaxf(acc[r], 0.f);
    }
    __syncthreads();

    {
        float acc[16];
        const float bias = ob2[t];
#pragma unroll
        for (int r = 0; r < 16; ++r) acc[r] = bias;
        const float* wrow = ow2 + (size_t)t * NOH;
#pragma unroll 2
        for (int hq = 0; hq < NOH / 4; ++hq) {
            const float4 w = ldg4(wrow + hq * 4);
#pragma unroll
            for (int r = 0; r < 16; ++r) {
                const float4 hv = *reinterpret_cast<const float4*>(&h1[r * NOH + hq * 4]);
                acc[r] += hv.x * w.x + hv.y * w.y + hv.z * w.z + hv.w * w.w;
            }
        }
#pragma unroll
        for (int r = 0; r < 16; ++r) h2[r * NOH + t] = fmaxf(acc[r], 0.f);
    }
    __syncthreads();

    {
        const int d  = t & 63;
        const int rg = t >> 6;
        float acc[4] = {0.f, 0.f, 0.f, 0.f};
        const float* wrow = ow3 + (size_t)d * NOH;
#pragma unroll 2
        for (int hq = 0; hq < NOH / 4; ++hq) {
            const float4 w = ldg4(wrow + hq * 4);
#pragma unroll
            for (int r = 0; r < 4; ++r) {
                const float4 hv = *reinterpret_cast<const float4*>(&h2[(rg * 4 + r) * NOH + hq * 4]);
                acc[r] += hv.x * w.x + hv.y * w.y + hv.z * w.z + hv.w * w.w;
            }
        }
        const float bias = ob3[d];
#pragma unroll
        for (int r = 0; r < 4; ++r) {
            const int n = n0 + rg * 4 + r;
            const size_t idx = ((size_t)b * NN + n) * ND + d;
            out[idx] = inputs[idx] + acc[r] + bias;
        }
    }
}

extern "C" void kernel_launch(void* const* d_in, const int* in_sizes, int n_in,
                              void* d_out, int out_size, void* d_ws, size_t ws_size,
                              hipStream_t stream)
{
    const float* inputs   = (const float*)d_in[0];
    const float* rel_rec  = (const float*)d_in[1];
    const float* rel_send = (const float*)d_in[2];
    const float* rel_type = (const float*)d_in[3];
    const int*   indices  = (const int*)  d_in[4];
    const float* w1  = (const float*)d_in[5];
    const float* b1  = (const float*)d_in[6];
    const float* w2  = (const float*)d_in[7];
    const float* b2  = (const float*)d_in[8];
    const float* w3  = (const float*)d_in[9];
    const float* b3  = (const float*)d_in[10];
    const float* w4  = (const float*)d_in[11];
    const float* b4  = (const float*)d_in[12];
    const float* ow1 = (const float*)d_in[13];
    const float* ob1 = (const float*)d_in[14];
    const float* ow2 = (const float*)d_in[15];
    const float* ob2 = (const float*)d_in[16];
    const float* ow3 = (const float*)d_in[17];
    const float* ob3 = (const float*)d_in[18];

    char* ws = (char*)d_ws;

    k_pre <<<dim3(382), dim3(256), 0, stream>>>(inputs, rel_rec, rel_send,
                                                w1, w3, ws);
    k_edge<<<dim3(256), dim3(512), 0, stream>>>(rel_type, indices,
                                                b1, b2, b3, b4, w2, w4, ws);
    k_out <<<dim3(256), dim3(256), 0, stream>>>((const ushort*)ws, inputs,
                                                ow1, ob1, ow2, ob2, ow3, ob3,
                                                (float*)d_out);
}